// Round 1
// baseline (53.607 us; speedup 1.0000x reference)
//
#include <hip/hip_runtime.h>

#define GRIDD 76      // grid dim (H = W)
#define NROWS 255     // anchors(3) * attrs(85)
#define ATTRS 85
#define PAD   77      // LDS row pitch (odd -> conflict-free transpose read)

__global__ __launch_bounds__(512, 2) void yolo_head_kernel(
    const float* __restrict__ x, const int* __restrict__ dimp,
    float* __restrict__ out)
{
    __shared__ float lds[NROWS * PAD];   // 255*77*4 = 78540 B
    const unsigned bh = blockIdx.x;          // b*76 + h
    const unsigned b  = bh / GRIDD;
    const unsigned h  = bh - b * GRIDD;
    const unsigned t  = threadIdx.x;
    const float stride = (float)(*dimp / GRIDD);   // 608/76 = 8

    // ---- load phase: [255][76] slab, coalesced float4 global loads ----
    const float* __restrict__ src =
        x + (size_t)b * (NROWS * GRIDD * GRIDD) + (size_t)h * GRIDD;
    const unsigned NV = NROWS * (GRIDD / 4);   // 255 * 19 = 4845 float4s
    for (unsigned i = t; i < NV; i += 512u) {
        unsigned row = i / 19u;
        unsigned c4  = (i - row * 19u) * 4u;
        const float4 v = *reinterpret_cast<const float4*>(
            src + (size_t)row * (GRIDD * GRIDD) + c4);
        float* l = &lds[row * PAD + c4];
        l[0] = v.x; l[1] = v.y; l[2] = v.z; l[3] = v.w;
    }
    __syncthreads();

    // ---- transform + transposed write: out[bh][w][a][attr], coalesced ----
    float* __restrict__ dst = out + (size_t)bh * (GRIDD * NROWS);
    const float fh = (float)h;
    const unsigned NOUT = GRIDD * NROWS;       // 19380, divisible by 4
    for (unsigned base = t * 4u; base < NOUT; base += 512u * 4u) {
        float r[4];
        #pragma unroll
        for (int k = 0; k < 4; ++k) {
            unsigned idx  = base + (unsigned)k;
            unsigned w    = idx / 255u;
            unsigned rem  = idx - w * 255u;    // a*85 + attr
            unsigned a    = rem / 85u;
            unsigned attr = rem - a * 85u;
            float v = lds[rem * PAD + w];
            float o;
            if (attr >= 4u) {
                // obj + classes: sigmoid
                o = __builtin_amdgcn_rcpf(1.0f + __expf(-v));
            } else if (attr < 2u) {
                // tx/ty: sigmoid*1.2 - 0.1 + grid offset, scaled to pixels
                float s   = __builtin_amdgcn_rcpf(1.0f + __expf(-v));
                float off = (attr == 0u) ? (float)w : fh;
                o = (s * 1.2f - 0.1f + off) * stride;
            } else {
                // tw/th: exp * raw anchor (anc/stride * stride cancels)
                float anc;
                if (attr == 2u) anc = (a == 0u) ? 12.f : ((a == 1u) ? 19.f : 40.f);
                else            anc = (a == 0u) ? 16.f : ((a == 1u) ? 36.f : 28.f);
                o = __expf(v) * anc;
            }
            r[k] = o;
        }
        *reinterpret_cast<float4*>(dst + base) = make_float4(r[0], r[1], r[2], r[3]);
    }
}

extern "C" void kernel_launch(void* const* d_in, const int* in_sizes, int n_in,
                              void* d_out, int out_size, void* d_ws, size_t ws_size,
                              hipStream_t stream) {
    const float* x  = (const float*)d_in[0];
    const int* dimp = (const int*)d_in[1];
    float* out      = (float*)d_out;
    const int B = in_sizes[0] / (NROWS * GRIDD * GRIDD);   // 16
    yolo_head_kernel<<<B * GRIDD, 512, 0, stream>>>(x, dimp, out);
}

// Round 2
// 43.590 us; speedup vs baseline: 1.2298x; 1.2298x over previous
//
#include <hip/hip_runtime.h>

#define GRIDD 76      // grid dim (H = W)
#define NROWS 255     // anchors(3) * attrs(85)
#define HALF  128     // rem rows staged per block (block half=1 overlaps rem=127)
#define PAD   77      // odd LDS pitch -> conflict-free stride-1-rem reads

__global__ __launch_bounds__(512, 8) void yolo_head_kernel(
    const float* __restrict__ x, const int* __restrict__ dimp,
    float* __restrict__ out)
{
    __shared__ float lds[HALF * PAD];   // 39424 B -> 4 blocks/CU
    const unsigned bid  = blockIdx.x;
    const unsigned b    = bid / (GRIDD * 2);
    const unsigned hr   = bid - b * (GRIDD * 2);
    const unsigned h    = hr >> 1;
    const unsigned half = hr & 1;
    const unsigned t    = threadIdx.x;
    const unsigned rbase = half * 127u;           // first staged rem row (overlap at 127)
    const float stride = (float)(*dimp / GRIDD);  // 608/76 = 8

    // ---- phase 1: stage [128 rem rows][76 w] slab, float4 global loads ----
    const float* __restrict__ src = x + (size_t)b * (NROWS * GRIDD * GRIDD)
                                      + (size_t)rbase * (GRIDD * GRIDD)
                                      + (size_t)h * GRIDD;
    const unsigned NV = HALF * 19u;   // 2432 float4s
    for (unsigned i = t; i < NV; i += 512u) {
        unsigned row = i / 19u;                 // compile-time magic div
        unsigned c4  = (i - row * 19u) * 4u;
        const float4 v = *reinterpret_cast<const float4*>(
            src + (size_t)row * (GRIDD * GRIDD) + c4);
        float* l = &lds[row * PAD + c4];
        l[0] = v.x; l[1] = v.y; l[2] = v.z; l[3] = v.w;
    }
    __syncthreads();

    // ---- phase 2: scalar transform + store; lane stride 1 in rem ----
    // LDS read: addr = r*77 + w, lane stride 77 (odd) -> 32 banks, conflict-free.
    // Store: consecutive lanes -> consecutive dwords, one 256B segment per wave.
    float* __restrict__ dst = out + (size_t)(b * GRIDD + h) * (GRIDD * NROWS) + rbase;
    const float fh = (float)h;
    #pragma unroll 4
    for (unsigned k = 0; k < 19u; ++k) {
        unsigned idx = t + k * 512u;            // 0 .. 9727  (76 w * 128 r)
        unsigned w   = idx >> 7;
        unsigned r   = idx & 127u;
        unsigned rem = rbase + r;               // 0..254
        float v = lds[r * PAD + w];
        unsigned a    = (rem >= 170u) ? 2u : ((rem >= 85u) ? 1u : 0u);
        unsigned attr = rem - a * 85u;
        float o;
        if (attr >= 4u) {
            // obj + classes: sigmoid
            o = __builtin_amdgcn_rcpf(1.0f + __expf(-v));
        } else if (attr < 2u) {
            // tx/ty: sigmoid*1.2 - 0.1 + grid offset, scaled to pixels
            float s   = __builtin_amdgcn_rcpf(1.0f + __expf(-v));
            float off = (attr == 0u) ? (float)w : fh;
            o = (s * 1.2f - 0.1f + off) * stride;
        } else {
            // tw/th: exp * raw anchor (anc/stride * stride cancels)
            float anc;
            if (attr == 2u) anc = (a == 0u) ? 12.f : ((a == 1u) ? 19.f : 40.f);
            else            anc = (a == 0u) ? 16.f : ((a == 1u) ? 36.f : 28.f);
            o = __expf(v) * anc;
        }
        dst[(size_t)w * NROWS + r] = o;
    }
}

extern "C" void kernel_launch(void* const* d_in, const int* in_sizes, int n_in,
                              void* d_out, int out_size, void* d_ws, size_t ws_size,
                              hipStream_t stream) {
    const float* x  = (const float*)d_in[0];
    const int* dimp = (const int*)d_in[1];
    float* out      = (float*)d_out;
    const int B = in_sizes[0] / (NROWS * GRIDD * GRIDD);   // 16
    yolo_head_kernel<<<B * GRIDD * 2, 512, 0, stream>>>(x, dimp, out);
}

// Round 3
// 42.788 us; speedup vs baseline: 1.2529x; 1.0187x over previous
//
#include <hip/hip_runtime.h>

#define GRIDD 76      // grid dim (H = W)
#define NROWS 255     // anchors(3) * attrs(85)
#define WROWS 16      // rem rows per wave
#define PAD   77      // odd pitch -> conflict-free lane-stride reads
#define GG    (GRIDD * GRIDD)   // 5776

__global__ __launch_bounds__(512, 8) void yolo_head_kernel(
    const float* __restrict__ x, const int* __restrict__ dimp,
    float* __restrict__ out)
{
    // wave-private LDS regions: no __syncthreads anywhere
    __shared__ float lds[8][WROWS * PAD];   // 8 * 4928 B = 39424 B -> 4 blocks/CU
    const unsigned bid  = blockIdx.x;
    const unsigned b    = bid / (GRIDD * 2);
    const unsigned hr   = bid - b * (GRIDD * 2);
    const unsigned h    = hr >> 1;
    const unsigned half = hr & 1;
    const unsigned t    = threadIdx.x;
    const unsigned wid  = t >> 6;
    const unsigned lane = t & 63u;
    const unsigned rbase = half * 127u + wid * WROWS;  // wave's first rem row
    const float stride = (float)(*dimp / GRIDD);       // 608/76 = 8

    float* lw = lds[wid];
    const float* __restrict__ src = x + (size_t)b * (NROWS * GG)
                                      + (size_t)rbase * GG + (size_t)h * GRIDD;

    // ---- phase 1: wave loads its 16 rows x 19 float4 (304 loads / 64 lanes) ----
    #pragma unroll
    for (unsigned it = 0; it < 5u; ++it) {
        unsigned i = it * 64u + lane;
        if (i < 304u) {
            unsigned row = i / 19u;
            unsigned c4  = (i - row * 19u) * 4u;
            const float4 v = *reinterpret_cast<const float4*>(
                src + (size_t)row * GG + c4);
            float* l = lw + row * PAD + c4;
            l[0] = v.x; l[1] = v.y; l[2] = v.z; l[3] = v.w;
        }
    }
    // wave-internal LDS sync: lanes are lockstep, DS ops drain in order
    asm volatile("s_waitcnt lgkmcnt(0)" ::: "memory");

    // ---- phase 2: rem is lane-invariant -> all attr logic hoists out ----
    const unsigned r    = lane & 15u;
    const unsigned wsub = lane >> 4;     // 4 w-values per store instruction
    const unsigned rem  = rbase + r;     // 0..254
    const unsigned a    = (rem >= 170u) ? 2u : ((rem >= 85u) ? 1u : 0u);
    const unsigned attr = rem - a * 85u;
    float anc = 0.f;
    if (attr == 2u) anc = (a == 0u) ? 12.f : ((a == 1u) ? 19.f : 40.f);
    if (attr == 3u) anc = (a == 0u) ? 16.f : ((a == 1u) ? 36.f : 28.f);
    const float fh = (float)h;
    const float* lr = lw + r * PAD;
    float* __restrict__ dst = out + (size_t)(b * GRIDD + h) * (GRIDD * NROWS) + rem;

    #pragma unroll
    for (unsigned k = 0; k < 19u; ++k) {
        unsigned w = wsub + 4u * k;
        float v = lr[w];                 // lane stride 77 (odd) -> conflict-free
        float o;
        if (attr >= 4u) {
            // obj + classes: sigmoid
            o = __builtin_amdgcn_rcpf(1.0f + __expf(-v));
        } else if (attr < 2u) {
            // tx/ty: (sigmoid*1.2 - 0.1 + offset) * stride
            float s   = __builtin_amdgcn_rcpf(1.0f + __expf(-v));
            float off = (attr == 0u) ? (float)w : fh;
            o = (s * 1.2f - 0.1f + off) * stride;
        } else {
            // tw/th: exp * raw anchor
            o = __expf(v) * anc;
        }
        dst[(size_t)w * NROWS] = o;      // lanes r stride 1 -> 64B runs, dense
    }
}

extern "C" void kernel_launch(void* const* d_in, const int* in_sizes, int n_in,
                              void* d_out, int out_size, void* d_ws, size_t ws_size,
                              hipStream_t stream) {
    const float* x  = (const float*)d_in[0];
    const int* dimp = (const int*)d_in[1];
    float* out      = (float*)d_out;
    const int B = in_sizes[0] / (NROWS * GG);   // 16
    yolo_head_kernel<<<B * GRIDD * 2, 512, 0, stream>>>(x, dimp, out);
}

// Round 4
// 37.855 us; speedup vs baseline: 1.4161x; 1.1303x over previous
//
#include <hip/hip_runtime.h>

#define GRIDD 76                 // grid dim (H = W)
#define NROWS 255                // anchors(3) * attrs(85)
#define HALF  128                // rem rows staged per block (half 1 overlaps rem=127)
#define PITCH 80                 // dwords; 16B-aligned rows -> ds_read_b128
#define GG    (GRIDD * GRIDD)    // 5776

__global__ __launch_bounds__(512, 8) void yolo_head_kernel(
    const float* __restrict__ x, const int* __restrict__ dimp,
    float* __restrict__ out)
{
    __shared__ float lds[HALF * PITCH];       // 40960 B -> exactly 4 blocks/CU
    // XCD-bijective swizzle: 2432 = 8 * 304. Consecutive logical blocks
    // (both halves of a column, neighboring h) land on the SAME XCD L2
    // so seam cache-lines merge before HBM writeback.
    const unsigned lb   = (blockIdx.x & 7u) * 304u + (blockIdx.x >> 3);
    const unsigned b    = lb / (GRIDD * 2);
    const unsigned hr   = lb - b * (GRIDD * 2);
    const unsigned h    = hr >> 1;
    const unsigned half = hr & 1;
    const unsigned t    = threadIdx.x;
    const unsigned rbase = half * 127u;                // staged rem rows rbase..rbase+127
    const float stride = (float)(*dimp / GRIDD);       // 608/76 = 8

    // ---- phase 1: stage [128 rem][76 w], coalesced float4 loads ----
    const float* __restrict__ src = x + (size_t)b * (NROWS * GG)
                                      + (size_t)rbase * GG + (size_t)h * GRIDD;
    for (unsigned i = t; i < HALF * 19u; i += 512u) {
        unsigned row = i / 19u;
        unsigned c4  = (i - row * 19u) * 4u;
        const float4 v = *reinterpret_cast<const float4*>(
            src + (size_t)row * GG + c4);
        *reinterpret_cast<float4*>(&lds[row * PITCH + c4]) = v;  // 16B-aligned
    }
    __syncthreads();

    // ---- phase 2: wave tiles of 64 rem x 4 w; lane = rem ----
    const unsigned wid  = t >> 6;
    const unsigned lane = t & 63u;
    const float fh = (float)h;
    const float mB = -0.1f * stride;
    float* __restrict__ outbh = out + (size_t)(b * GRIDD + h) * (GRIDD * NROWS);

    for (unsigned tt = wid; tt < 38u; tt += 8u) {
        const unsigned rc = tt & 1u;
        const unsigned wc = tt >> 1;              // 0..18, covers w = 4*wc..4*wc+3
        const unsigned r  = (rc << 6) + lane;     // LDS row 0..127
        const unsigned rem = rbase + r;           // 0..254
        // hoisted per-tile attr logic (lane-fixed across the w loop)
        const unsigned a    = (rem >= 170u) ? 2u : ((rem >= 85u) ? 1u : 0u);
        const unsigned attr = rem - a * 85u;
        const bool  wh  = (attr == 2u) | (attr == 3u);
        const bool  isx = (attr == 0u);
        float anc = 0.f;
        if (attr == 2u) anc = (a == 0u) ? 12.f : ((a == 1u) ? 19.f : 40.f);
        if (attr == 3u) anc = (a == 0u) ? 16.f : ((a == 1u) ? 36.f : 28.f);
        const float sgn = wh ? 1.f : -1.f;
        const float A   = (attr < 2u) ? 1.2f * stride : 1.f;
        const float B0  = (attr == 1u) ? (fh * stride + mB) : 0.f;

        const float4 vv = *reinterpret_cast<const float4*>(&lds[r * PITCH + wc * 4u]);
        float* __restrict__ dst = outbh + rem;
        #pragma unroll
        for (unsigned i = 0; i < 4u; ++i) {
            const float v = (i == 0) ? vv.x : (i == 1) ? vv.y : (i == 2) ? vv.z : vv.w;
            const float w = (float)(4u * wc + i);
            const float e = __expf(sgn * v);
            const float sig = __builtin_amdgcn_rcpf(1.0f + e);
            const float Bi  = isx ? fmaf(w, stride, mB) : B0;
            const float o   = wh ? e * anc : fmaf(sig, A, Bi);
            dst[(size_t)(4u * wc + i) * NROWS] = o;   // 64-lane 256B contiguous run
        }
    }
}

extern "C" void kernel_launch(void* const* d_in, const int* in_sizes, int n_in,
                              void* d_out, int out_size, void* d_ws, size_t ws_size,
                              hipStream_t stream) {
    const float* x  = (const float*)d_in[0];
    const int* dimp = (const int*)d_in[1];
    float* out      = (float*)d_out;
    const int B = in_sizes[0] / (NROWS * GG);   // 16
    yolo_head_kernel<<<B * GRIDD * 2, 512, 0, stream>>>(x, dimp, out);
}